// Round 8
// baseline (134.014 us; speedup 1.0000x reference)
//
#include <hip/hip_runtime.h>
#include <hip/hip_bf16.h>

#define B_ 8
#define S_ 2048
#define F_ 1024
#define DK_ 128
#define M_ (B_*S_)          // 16384

typedef unsigned short u16;
typedef short short8 __attribute__((ext_vector_type(8)));
typedef float f32x4 __attribute__((ext_vector_type(4)));
typedef float f32x16 __attribute__((ext_vector_type(16)));

__device__ __forceinline__ u16 f2bf(float f) {
    unsigned int u = __float_as_uint(f);
    u += 0x7FFFu + ((u >> 16) & 1u);    // round-to-nearest-even
    return (u16)(u >> 16);
}
__device__ __forceinline__ unsigned int pack2(float a, float b) {
    return (unsigned int)f2bf(a) | ((unsigned int)f2bf(b) << 16);
}
__device__ __forceinline__ float fexp2(float x) {
#if __has_builtin(__builtin_amdgcn_exp2f)
    return __builtin_amdgcn_exp2f(x);   // raw v_exp_f32 (2^x)
#else
    return exp2f(x);
#endif
}
__device__ __forceinline__ unsigned int cvt_pk_bf16(float lo, float hi) {
    unsigned int r;
    asm volatile("v_cvt_pk_bf16_f32 %0, %1, %2" : "=v"(r) : "v"(lo), "v"(hi));
    return r;
}

// ---------------------------------------------------------------------------
// Kernel 1: W [1024][128] fp32 -> WT [3][128][1024] bf16 (transposed).
// w_q gets (1/sqrt(128)) * log2(e) folded in, so softmax uses raw exp2.
// ---------------------------------------------------------------------------
__global__ __launch_bounds__(256) void prep_wt(const float* __restrict__ wq,
                                               const float* __restrict__ wk,
                                               const float* __restrict__ wv,
                                               u16* __restrict__ WT) {
    int id = blockIdx.x * 256 + threadIdx.x;
    if (id >= 3 * DK_ * F_) return;
    int m   = id / (DK_ * F_);
    int rem = id - m * (DK_ * F_);
    int c   = rem / F_;
    int k   = rem - c * F_;
    const float* w = (m == 0) ? wq : (m == 1) ? wk : wv;
    float v = w[k * DK_ + c];
    if (m == 0) v *= 0.12751741951f;   // (1/sqrt(128)) * log2(e)
    WT[id] = f2bf(v);
}

// ---------------------------------------------------------------------------
// Kernel 2: projection GEMM — reverted verbatim to the R2-R5/R6 version
// (~20 us unprofiled; R7's "barrier-amortized" restructure was +16 us).
// mode 0: qp [16384][128], mode 1: kp [16384][128], mode 2: vpT [128][16384]
// ---------------------------------------------------------------------------
__global__ __launch_bounds__(256, 3) void proj(const float* __restrict__ xq,
                                               const float* __restrict__ xk,
                                               const float* __restrict__ xv,
                                               const u16* __restrict__ WT,
                                               u16* __restrict__ qp,
                                               u16* __restrict__ kp,
                                               u16* __restrict__ vpT) {
    const int mode = blockIdx.y;
    const float* X = (mode == 0) ? xq : (mode == 1) ? xk : xv;
    const u16*   W = WT + mode * (DK_ * F_);

    __shared__ u16 a_lds[64][40];    // row stride 80B (16B-aligned), bank-spread
    __shared__ u16 w_lds[128][40];

    const int t    = threadIdx.x;
    const int lane = t & 63;
    const int wv_  = t >> 6;
    const int l15  = lane & 15, l4 = lane >> 4;
    const int row0 = blockIdx.x * 64;

    f32x4 acc[8];
#pragma unroll
    for (int j = 0; j < 8; ++j) acc[j] = f32x4{0.f, 0.f, 0.f, 0.f};

    for (int k0 = 0; k0 < F_; k0 += 32) {
        {
            int r = t >> 2, kk = (t & 3) * 8;
            const float4* src = (const float4*)(X + (size_t)(row0 + r) * F_ + k0 + kk);
            float4 f0 = src[0], f1 = src[1];
            int4 o0;
            o0.x = pack2(f0.x, f0.y); o0.y = pack2(f0.z, f0.w);
            o0.z = pack2(f1.x, f1.y); o0.w = pack2(f1.z, f1.w);
            *(int4*)&a_lds[r][kk] = o0;
        }
        {
            int c = t >> 1, kk = (t & 1) * 16;
            const int4* src = (const int4*)(W + (size_t)c * F_ + k0 + kk);
            *(int4*)&w_lds[c][kk]     = src[0];
            *(int4*)&w_lds[c][kk + 8] = src[1];
        }
        __syncthreads();

        short8 af = *(const short8*)&a_lds[wv_ * 16 + l15][l4 * 8];
        short8 bf[8];
#pragma unroll
        for (int ct = 0; ct < 8; ++ct)
            bf[ct] = *(const short8*)&w_lds[ct * 16 + l15][l4 * 8];

        if (mode < 2) {
#pragma unroll
            for (int ct = 0; ct < 8; ++ct)
                acc[ct] = __builtin_amdgcn_mfma_f32_16x16x32_bf16(af, bf[ct], acc[ct], 0, 0, 0);
        } else {
#pragma unroll
            for (int ct = 0; ct < 8; ++ct)
                acc[ct] = __builtin_amdgcn_mfma_f32_16x16x32_bf16(bf[ct], af, acc[ct], 0, 0, 0);
        }
        __syncthreads();
    }

    if (mode < 2) {
        u16* OUT = (mode == 0) ? qp : kp;
#pragma unroll
        for (int ct = 0; ct < 8; ++ct)
#pragma unroll
            for (int r = 0; r < 4; ++r) {
                int row = row0 + wv_ * 16 + l4 * 4 + r;
                int col = ct * 16 + l15;
                OUT[(size_t)row * DK_ + col] = f2bf(acc[ct][r]);
            }
    } else {
#pragma unroll
        for (int ct = 0; ct < 8; ++ct)
#pragma unroll
            for (int r = 0; r < 4; ++r) {
                int n = ct * 16 + l4 * 4 + r;
                int m = row0 + wv_ * 16 + l15;
                vpT[(size_t)n * M_ + m] = f2bf(acc[ct][r]);
            }
    }
}

// ---------------------------------------------------------------------------
// Kernel 3: flash attention, swapped-operand 32x32x16, WAVE-PAIRED to fit
// the 128-VGPR cap (R6's version needed ~160 -> spilled -> ~89 us).
// 8 waves = 4 kv-slices (512 kv each) x 2 d-halves. Paired waves (slice,
// slice+4) duplicate QK^T+softmax (cheap) but each accumulates only 64 of
// the 128 d-dims: o4[2]=32 regs, vf[2][2]=8 regs -> ~116 total, no spill.
// Grid 512 (b=blk&7 XCD-pins KV), per-lane softmax, P in-register.
// ---------------------------------------------------------------------------
__global__ __launch_bounds__(512, 2) void attn(const u16* __restrict__ qp,
                                               const u16* __restrict__ kp,
                                               const u16* __restrict__ vpT,
                                               float* __restrict__ out) {
    __shared__ float oA[128 * 33], oB[128 * 33];
    __shared__ float m_lds[4][32], l_lds[4][32], gm_lds[32], gl_lds[32];

    const int t     = threadIdx.x;
    const int lane  = t & 63;
    const int wv_   = t >> 6;                // 0..7
    const int slice = wv_ & 3;               // kv slice 0..3
    const int half  = wv_ >> 2;              // d half: 0 -> d 0..63, 1 -> d 64..127
    const int r31   = lane & 31;
    const int hi    = lane >> 5;

    const int b  = blockIdx.x & 7;
    const int qi = blockIdx.x >> 3;
    const int qbase = b * S_ + qi * 32;

    // Q as persistent B-fragments: qf[c] = Q[q=r31][d = c*16 + hi*8 + 0..7]
    short8 qf[8];
#pragma unroll
    for (int c = 0; c < 8; ++c)
        qf[c] = *(const short8*)(qp + (size_t)(qbase + r31) * DK_ + c * 16 + hi * 8);

    f32x16 o4[2];
#pragma unroll
    for (int ct = 0; ct < 2; ++ct)
#pragma unroll
        for (int i = 0; i < 16; ++i) o4[ct][i] = 0.f;
    float mrun = -1.0e30f, lrun = 0.f;

    const int kv_lo = b * S_ + slice * 512;

    for (int kt = 0; kt < 16; ++kt) {
        const int kv0 = kv_lo + kt * 32;

        // ---- K tile A-frags (row=kv=r31, k=d); V^T A-frags for this d-half
        short8 kf[8];
#pragma unroll
        for (int c = 0; c < 8; ++c)
            kf[c] = *(const short8*)(kp + (size_t)(kv0 + r31) * DK_ + c * 16 + hi * 8);
        short8 vf[2][2];
#pragma unroll
        for (int ct = 0; ct < 2; ++ct)
#pragma unroll
            for (int ch = 0; ch < 2; ++ch)
                vf[ct][ch] = *(const short8*)(vpT + (size_t)(half * 64 + ct * 32 + r31) * M_
                                                  + kv0 + ch * 16 + hi * 8);

        // ---- QK^T: st[reg] = S^T[kv = (reg&3)+8*(reg>>2)+4*hi][q = r31]
        f32x16 st;
#pragma unroll
        for (int i = 0; i < 16; ++i) st[i] = 0.f;
#pragma unroll
        for (int c = 0; c < 8; ++c)
            st = __builtin_amdgcn_mfma_f32_32x32x16_bf16(kf[c], qf[c], st, 0, 0, 0);

        // ---- per-lane softmax (scores already in log2 units); p reuses st
        float tm = st[0];
#pragma unroll
        for (int i = 1; i < 16; ++i) tm = fmaxf(tm, st[i]);
        tm = fmaxf(tm, __shfl_xor(tm, 32, 64));
        if (__any(tm > mrun + 8.0f)) {       // defer-max
            float mn = fmaxf(mrun, tm);
            float fs = fexp2(mrun - mn);
            mrun = mn;
            lrun *= fs;
#pragma unroll
            for (int ct = 0; ct < 2; ++ct)
#pragma unroll
                for (int i = 0; i < 16; ++i) o4[ct][i] *= fs;
        }
        float sum = 0.f;
#pragma unroll
        for (int i = 0; i < 16; ++i) { st[i] = fexp2(st[i] - mrun); sum += st[i]; }
        sum += __shfl_xor(sum, 32, 64);
        lrun += sum;

        // ---- P -> bf16 B-fragments in-register
        short8 bp[2];
#pragma unroll
        for (int ch = 0; ch < 2; ++ch) {
            unsigned int wa = cvt_pk_bf16(st[ch * 8 + 0], st[ch * 8 + 1]);
            unsigned int wb = cvt_pk_bf16(st[ch * 8 + 2], st[ch * 8 + 3]);
            unsigned int wc = cvt_pk_bf16(st[ch * 8 + 4], st[ch * 8 + 5]);
            unsigned int wd = cvt_pk_bf16(st[ch * 8 + 6], st[ch * 8 + 7]);
            unsigned int xa = (unsigned int)__shfl_xor((int)wa, 32, 64);
            unsigned int xb = (unsigned int)__shfl_xor((int)wb, 32, 64);
            unsigned int xc = (unsigned int)__shfl_xor((int)wc, 32, 64);
            unsigned int xd = (unsigned int)__shfl_xor((int)wd, 32, 64);
            int4 w;
            w.x = (int)(hi ? xc : wa);
            w.y = (int)(hi ? xd : wb);
            w.z = (int)(hi ? wc : xa);
            w.w = (int)(hi ? wd : xb);
            bp[ch] = *(short8*)&w;
        }

        // ---- PV (this d-half only): O^T[d][q] += V^T x P^T
#pragma unroll
        for (int ct = 0; ct < 2; ++ct) {
            o4[ct] = __builtin_amdgcn_mfma_f32_32x32x16_bf16(vf[ct][0], bp[0], o4[ct], 0, 0, 0);
            o4[ct] = __builtin_amdgcn_mfma_f32_32x32x16_bf16(vf[ct][1], bp[1], o4[ct], 0, 0, 0);
        }
    }

    // ---- cross-slice combine (4 partials over kv; halves share m/l) ----
    if (half == 0 && lane < 32) {
        m_lds[slice][r31] = mrun;
        l_lds[slice][r31] = lrun;
    }
    __syncthreads();
    if (t < 32) {
        float gm = -1.0e30f;
#pragma unroll
        for (int w = 0; w < 4; ++w) gm = fmaxf(gm, m_lds[w][t]);
        float gl = 0.f;
#pragma unroll
        for (int w = 0; w < 4; ++w)
            gl += l_lds[w][t] * fexp2(m_lds[w][t] - gm);
        gm_lds[t] = gm;
        gl_lds[t] = gl;
    }
    __syncthreads();

    const float sc = fexp2(mrun - gm_lds[r31]);
    float* slot = (slice & 2) ? oB : oA;     // slices 0,1 -> A; 2,3 -> B
    if (!(slice & 1)) {                      // round 0: slices 0,2 write
#pragma unroll
        for (int ct = 0; ct < 2; ++ct)
#pragma unroll
            for (int i = 0; i < 16; ++i) {
                int d = half * 64 + ct * 32 + (i & 3) + 8 * (i >> 2) + 4 * hi;
                slot[d * 33 + r31] = o4[ct][i] * sc;
            }
    }
    __syncthreads();
    if (slice & 1) {                         // round 1: slices 1,3 accumulate
#pragma unroll
        for (int ct = 0; ct < 2; ++ct)
#pragma unroll
            for (int i = 0; i < 16; ++i) {
                int d = half * 64 + ct * 32 + (i & 3) + 8 * (i >> 2) + 4 * hi;
                slot[d * 33 + r31] += o4[ct][i] * sc;
            }
    }
    __syncthreads();

    // ---- final: (oA+oB)/gl, transpose O^T -> out[q][d]
    {
        int qq = t & 31, d0 = (t >> 5) * 8;
        float inv = 1.0f / gl_lds[qq];
        float* dst = out + (size_t)(qbase + qq) * DK_ + d0;
        float4 v0, v1;
        v0.x = (oA[(d0 + 0) * 33 + qq] + oB[(d0 + 0) * 33 + qq]) * inv;
        v0.y = (oA[(d0 + 1) * 33 + qq] + oB[(d0 + 1) * 33 + qq]) * inv;
        v0.z = (oA[(d0 + 2) * 33 + qq] + oB[(d0 + 2) * 33 + qq]) * inv;
        v0.w = (oA[(d0 + 3) * 33 + qq] + oB[(d0 + 3) * 33 + qq]) * inv;
        v1.x = (oA[(d0 + 4) * 33 + qq] + oB[(d0 + 4) * 33 + qq]) * inv;
        v1.y = (oA[(d0 + 5) * 33 + qq] + oB[(d0 + 5) * 33 + qq]) * inv;
        v1.z = (oA[(d0 + 6) * 33 + qq] + oB[(d0 + 6) * 33 + qq]) * inv;
        v1.w = (oA[(d0 + 7) * 33 + qq] + oB[(d0 + 7) * 33 + qq]) * inv;
        *(float4*)(dst)     = v0;
        *(float4*)(dst + 4) = v1;
    }
}

// ---------------------------------------------------------------------------
extern "C" void kernel_launch(void* const* d_in, const int* in_sizes, int n_in,
                              void* d_out, int out_size, void* d_ws, size_t ws_size,
                              hipStream_t stream) {
    const float* q  = (const float*)d_in[0];
    const float* k  = (const float*)d_in[1];
    const float* v  = (const float*)d_in[2];
    const float* wq = (const float*)d_in[3];
    const float* wk = (const float*)d_in[4];
    const float* wv = (const float*)d_in[5];
    float* out = (float*)d_out;

    char* ws = (char*)d_ws;
    u16* WT  = (u16*)ws;                                   // 786432 B
    u16* qp  = (u16*)(ws + 786432);                        // 4 MB
    u16* kp  = (u16*)(ws + 786432 + 4194304);              // 4 MB
    u16* vpT = (u16*)(ws + 786432 + 2 * 4194304);          // 4 MB

    prep_wt<<<dim3(1536), dim3(256), 0, stream>>>(wq, wk, wv, WT);
    proj<<<dim3(256, 3), dim3(256), 0, stream>>>(q, k, v, WT, qp, kp, vpT);
    attn<<<dim3(512), dim3(512), 0, stream>>>(qp, kp, vpT, out);
}

// Round 9
// 82.459 us; speedup vs baseline: 1.6252x; 1.6252x over previous
//
#include <hip/hip_runtime.h>
#include <hip/hip_bf16.h>

#define B_ 8
#define S_ 2048
#define F_ 1024
#define DK_ 128
#define M_ (B_*S_)          // 16384

typedef unsigned short u16;
typedef short short8 __attribute__((ext_vector_type(8)));
typedef float f32x4 __attribute__((ext_vector_type(4)));
typedef float f32x16 __attribute__((ext_vector_type(16)));

__device__ __forceinline__ u16 f2bf(float f) {
    unsigned int u = __float_as_uint(f);
    u += 0x7FFFu + ((u >> 16) & 1u);    // round-to-nearest-even
    return (u16)(u >> 16);
}
__device__ __forceinline__ unsigned int pack2(float a, float b) {
    return (unsigned int)f2bf(a) | ((unsigned int)f2bf(b) << 16);
}
__device__ __forceinline__ float fexp2(float x) {
#if __has_builtin(__builtin_amdgcn_exp2f)
    return __builtin_amdgcn_exp2f(x);   // raw v_exp_f32 (2^x)
#else
    return exp2f(x);
#endif
}
__device__ __forceinline__ unsigned int cvt_pk_bf16(float lo, float hi) {
    unsigned int r;
    asm volatile("v_cvt_pk_bf16_f32 %0, %1, %2" : "=v"(r) : "v"(lo), "v"(hi));
    return r;
}

// ---------------------------------------------------------------------------
// Kernel 1: W [1024][128] fp32 -> WT [3][128][1024] bf16 (transposed).
// w_q gets (1/sqrt(128)) * log2(e) folded in, so softmax uses raw exp2.
// ---------------------------------------------------------------------------
__global__ __launch_bounds__(256) void prep_wt(const float* __restrict__ wq,
                                               const float* __restrict__ wk,
                                               const float* __restrict__ wv,
                                               u16* __restrict__ WT) {
    int id = blockIdx.x * 256 + threadIdx.x;
    if (id >= 3 * DK_ * F_) return;
    int m   = id / (DK_ * F_);
    int rem = id - m * (DK_ * F_);
    int c   = rem / F_;
    int k   = rem - c * F_;
    const float* w = (m == 0) ? wq : (m == 1) ? wk : wv;
    float v = w[k * DK_ + c];
    if (m == 0) v *= 0.12751741951f;   // (1/sqrt(128)) * log2(e)
    WT[id] = f2bf(v);
}

// ---------------------------------------------------------------------------
// Kernel 2: projection GEMM (proven R2-R6 version, unchanged).
// mode 0: qp [16384][128], mode 1: kp [16384][128], mode 2: vpT [128][16384]
// ---------------------------------------------------------------------------
__global__ __launch_bounds__(256, 3) void proj(const float* __restrict__ xq,
                                               const float* __restrict__ xk,
                                               const float* __restrict__ xv,
                                               const u16* __restrict__ WT,
                                               u16* __restrict__ qp,
                                               u16* __restrict__ kp,
                                               u16* __restrict__ vpT) {
    const int mode = blockIdx.y;
    const float* X = (mode == 0) ? xq : (mode == 1) ? xk : xv;
    const u16*   W = WT + mode * (DK_ * F_);

    __shared__ u16 a_lds[64][40];
    __shared__ u16 w_lds[128][40];

    const int t    = threadIdx.x;
    const int lane = t & 63;
    const int wv_  = t >> 6;
    const int l15  = lane & 15, l4 = lane >> 4;
    const int row0 = blockIdx.x * 64;

    f32x4 acc[8];
#pragma unroll
    for (int j = 0; j < 8; ++j) acc[j] = f32x4{0.f, 0.f, 0.f, 0.f};

    for (int k0 = 0; k0 < F_; k0 += 32) {
        {
            int r = t >> 2, kk = (t & 3) * 8;
            const float4* src = (const float4*)(X + (size_t)(row0 + r) * F_ + k0 + kk);
            float4 f0 = src[0], f1 = src[1];
            int4 o0;
            o0.x = pack2(f0.x, f0.y); o0.y = pack2(f0.z, f0.w);
            o0.z = pack2(f1.x, f1.y); o0.w = pack2(f1.z, f1.w);
            *(int4*)&a_lds[r][kk] = o0;
        }
        {
            int c = t >> 1, kk = (t & 1) * 16;
            const int4* src = (const int4*)(W + (size_t)c * F_ + k0 + kk);
            *(int4*)&w_lds[c][kk]     = src[0];
            *(int4*)&w_lds[c][kk + 8] = src[1];
        }
        __syncthreads();

        short8 af = *(const short8*)&a_lds[wv_ * 16 + l15][l4 * 8];
        short8 bf[8];
#pragma unroll
        for (int ct = 0; ct < 8; ++ct)
            bf[ct] = *(const short8*)&w_lds[ct * 16 + l15][l4 * 8];

        if (mode < 2) {
#pragma unroll
            for (int ct = 0; ct < 8; ++ct)
                acc[ct] = __builtin_amdgcn_mfma_f32_16x16x32_bf16(af, bf[ct], acc[ct], 0, 0, 0);
        } else {
#pragma unroll
            for (int ct = 0; ct < 8; ++ct)
                acc[ct] = __builtin_amdgcn_mfma_f32_16x16x32_bf16(bf[ct], af, acc[ct], 0, 0, 0);
        }
        __syncthreads();
    }

    if (mode < 2) {
        u16* OUT = (mode == 0) ? qp : kp;
#pragma unroll
        for (int ct = 0; ct < 8; ++ct)
#pragma unroll
            for (int r = 0; r < 4; ++r) {
                int row = row0 + wv_ * 16 + l4 * 4 + r;
                int col = ct * 16 + l15;
                OUT[(size_t)row * DK_ + col] = f2bf(acc[ct][r]);
            }
    } else {
#pragma unroll
        for (int ct = 0; ct < 8; ++ct)
#pragma unroll
            for (int r = 0; r < 4; ++r) {
                int n = ct * 16 + l4 * 4 + r;
                int m = row0 + wv_ * 16 + l15;
                vpT[(size_t)n * M_ + m] = f2bf(acc[ct][r]);
            }
    }
}

// ---------------------------------------------------------------------------
// Kernel 3: flash attention v3 — LDS-staged K/V (the R4/R6/R8 ~100us was the
// CU's L1/TA saturating on per-wave fragment GATHERS: each short8 frag load
// touches 32 distinct cache lines. Staging converts those to coalesced
// global loads + swizzled ds_read_b128).
// Grid 256: b = blk&7 (XCD-pin), qi = blk>>3 -> 64 q rows.
// Block 512 thr = 8 waves = (q_sub 2) x (kv_sub 2) x (d_half 2).
// Per 64-kv tile: stage K[64][128] + V^T[128][64] (dbuf, XOR-swizzled),
// 1 barrier/iter, tile k+1 loads issued before compute of tile k.
// QK^T duplicated x2 over d_half so P stays in-register (R8 math verbatim).
// ---------------------------------------------------------------------------
union attn_lds_t {
    struct {
        __align__(16) unsigned char kbuf[2][16384];  // [64 kv][256B], swz: col16 ^= row&15
        __align__(16) unsigned char vbuf[2][16384];  // [128 d][128B], swz: chunk ^= row&7
    } s;
    struct { float ob[64][132]; } e;                 // epilogue combine (33.8 KB)
};

__global__ __launch_bounds__(512, 2) void attn(const u16* __restrict__ qp,
                                               const u16* __restrict__ kp,
                                               const u16* __restrict__ vpT,
                                               float* __restrict__ out) {
    __shared__ attn_lds_t u;
    __shared__ float m_lds[4][32], l_lds[4][32], gm_lds[2][32], gl_lds[2][32];

    const int t      = threadIdx.x;
    const int lane   = t & 63;
    const int wv_    = t >> 6;              // 0..7
    const int q_sub  = wv_ & 1;
    const int kv_sub = (wv_ >> 1) & 1;
    const int d_half = wv_ >> 2;
    const int r31    = lane & 31;
    const int hi     = lane >> 5;

    const int b  = blockIdx.x & 7;
    const int qi = blockIdx.x >> 3;          // 0..31
    const int qrow0 = b * S_ + qi * 64;
    const int kvb0  = b * S_;

    // Q as persistent B-fragments: qf[c] = Q[q][d = c*16 + hi*8 + 0..7]
    short8 qf[8];
#pragma unroll
    for (int c = 0; c < 8; ++c)
        qf[c] = *(const short8*)(qp + (size_t)(qrow0 + q_sub * 32 + r31) * DK_
                                    + c * 16 + hi * 8);

    f32x16 o4[2];
#pragma unroll
    for (int ct = 0; ct < 2; ++ct)
#pragma unroll
        for (int i = 0; i < 16; ++i) o4[ct][i] = 0.f;
    float mrun = -1.0e30f, lrun = 0.f;

    // staging registers
    int4 gk0, gk1, gv0, gv1;
    const int f0 = t, f1 = 512 + t;
    const int kr0 = f0 >> 4, kc0 = f0 & 15, kr1 = f1 >> 4, kc1 = f1 & 15;
    const int vr0 = f0 >> 3, vc0 = f0 & 7,  vr1 = f1 >> 3, vc1 = f1 & 7;

#define LOADT(kvb)                                                               \
    {                                                                            \
        gk0 = *(const int4*)(kp + (size_t)((kvb) + kr0) * DK_ + kc0 * 8);        \
        gk1 = *(const int4*)(kp + (size_t)((kvb) + kr1) * DK_ + kc1 * 8);        \
        gv0 = *(const int4*)(vpT + (size_t)vr0 * M_ + (kvb) + vc0 * 8);          \
        gv1 = *(const int4*)(vpT + (size_t)vr1 * M_ + (kvb) + vc1 * 8);          \
    }
#define WRITET(nb)                                                               \
    {                                                                            \
        *(int4*)(u.s.kbuf[nb] + kr0 * 256 + ((kc0 ^ (kr0 & 15)) << 4)) = gk0;    \
        *(int4*)(u.s.kbuf[nb] + kr1 * 256 + ((kc1 ^ (kr1 & 15)) << 4)) = gk1;    \
        *(int4*)(u.s.vbuf[nb] + vr0 * 128 + ((vc0 ^ (vr0 & 7)) << 4)) = gv0;     \
        *(int4*)(u.s.vbuf[nb] + vr1 * 128 + ((vc1 ^ (vr1 & 7)) << 4)) = gv1;     \
    }

    // prologue: stage tile 0 into buf 0
    LOADT(kvb0);
    WRITET(0);
    int cur = 0;

    for (int kt = 0; kt < 32; ++kt) {
        if (kt < 31) LOADT(kvb0 + (kt + 1) * 64);
        __syncthreads();                     // buf[cur] writes visible

        const unsigned char* kb = u.s.kbuf[cur];
        const unsigned char* vb = u.s.vbuf[cur];

        // ---- K fragments from LDS (swizzled)
        const int krow  = kv_sub * 32 + r31;
        const int kbase = krow * 256;
        const int ksw   = krow & 15;
        short8 kf[8];
#pragma unroll
        for (int c = 0; c < 8; ++c)
            kf[c] = *(const short8*)(kb + kbase + (((c * 2 + hi) ^ ksw) << 4));

        // ---- QK^T: st[i] = S^T[kv_local = (i&3)+8*(i>>2)+4*hi][q = r31]
        f32x16 st;
#pragma unroll
        for (int i = 0; i < 16; ++i) st[i] = 0.f;
#pragma unroll
        for (int c = 0; c < 8; ++c)
            st = __builtin_amdgcn_mfma_f32_32x32x16_bf16(kf[c], qf[c], st, 0, 0, 0);

        // ---- per-lane online softmax (scores in log2 units)
        float tm = st[0];
#pragma unroll
        for (int i = 1; i < 16; ++i) tm = fmaxf(tm, st[i]);
        tm = fmaxf(tm, __shfl_xor(tm, 32, 64));
        if (__any(tm > mrun + 8.0f)) {       // defer-max
            float mn = fmaxf(mrun, tm);
            float fs = fexp2(mrun - mn);
            mrun = mn;
            lrun *= fs;
#pragma unroll
            for (int ct = 0; ct < 2; ++ct)
#pragma unroll
                for (int i = 0; i < 16; ++i) o4[ct][i] *= fs;
        }
        float sum = 0.f;
#pragma unroll
        for (int i = 0; i < 16; ++i) { st[i] = fexp2(st[i] - mrun); sum += st[i]; }
        sum += __shfl_xor(sum, 32, 64);
        lrun += sum;

        // ---- P -> bf16 B-fragments in-register (R8 verbatim)
        short8 bp[2];
#pragma unroll
        for (int ch = 0; ch < 2; ++ch) {
            unsigned int wa = cvt_pk_bf16(st[ch * 8 + 0], st[ch * 8 + 1]);
            unsigned int wb = cvt_pk_bf16(st[ch * 8 + 2], st[ch * 8 + 3]);
            unsigned int wc = cvt_pk_bf16(st[ch * 8 + 4], st[ch * 8 + 5]);
            unsigned int wd = cvt_pk_bf16(st[ch * 8 + 6], st[ch * 8 + 7]);
            unsigned int xa = (unsigned int)__shfl_xor((int)wa, 32, 64);
            unsigned int xb = (unsigned int)__shfl_xor((int)wb, 32, 64);
            unsigned int xc = (unsigned int)__shfl_xor((int)wc, 32, 64);
            unsigned int xd = (unsigned int)__shfl_xor((int)wd, 32, 64);
            int4 w;
            w.x = (int)(hi ? xc : wa);
            w.y = (int)(hi ? xd : wb);
            w.z = (int)(hi ? wc : xa);
            w.w = (int)(hi ? wd : xb);
            bp[ch] = *(short8*)&w;
        }

        // ---- PV from LDS V^T (this wave's d_half, kv_sub)
#pragma unroll
        for (int ct = 0; ct < 2; ++ct) {
            const int vrow  = d_half * 64 + ct * 32 + r31;
            const int vbase = vrow * 128;
            const int vsw   = vrow & 7;
#pragma unroll
            for (int ch = 0; ch < 2; ++ch) {
                short8 vf = *(const short8*)(vb + vbase
                                             + (((kv_sub * 4 + ch * 2 + hi) ^ vsw) << 4));
                o4[ct] = __builtin_amdgcn_mfma_f32_32x32x16_bf16(vf, bp[ch], o4[ct], 0, 0, 0);
            }
        }

        if (kt < 31) WRITET(cur ^ 1);
        cur ^= 1;
    }
#undef LOADT
#undef WRITET

    // ---- epilogue: combine kv_sub partials ----
    __syncthreads();                          // done with stage bufs (union reuse)
    if (d_half == 0 && lane < 32) {
        m_lds[q_sub * 2 + kv_sub][r31] = mrun;
        l_lds[q_sub * 2 + kv_sub][r31] = lrun;
    }
    __syncthreads();
    if (t < 64) {
        int qs = t >> 5, qq = t & 31;
        float m0 = m_lds[qs * 2][qq], m1 = m_lds[qs * 2 + 1][qq];
        float gm = fmaxf(m0, m1);
        float gl = l_lds[qs * 2][qq] * fexp2(m0 - gm)
                 + l_lds[qs * 2 + 1][qq] * fexp2(m1 - gm);
        gm_lds[qs][qq] = gm;
        gl_lds[qs][qq] = gl;
    }
    __syncthreads();

    const float sc = fexp2(mrun - gm_lds[q_sub][r31]);
    const int qrow = q_sub * 32 + r31;
    if (kv_sub == 0) {
#pragma unroll
        for (int ct = 0; ct < 2; ++ct)
#pragma unroll
            for (int i = 0; i < 16; ++i) {
                int d = d_half * 64 + ct * 32 + (i & 3) + 8 * (i >> 2) + 4 * hi;
                u.e.ob[qrow][d] = o4[ct][i] * sc;
            }
    }
    __syncthreads();
    if (kv_sub == 1) {
#pragma unroll
        for (int ct = 0; ct < 2; ++ct)
#pragma unroll
            for (int i = 0; i < 16; ++i) {
                int d = d_half * 64 + ct * 32 + (i & 3) + 8 * (i >> 2) + 4 * hi;
                u.e.ob[qrow][d] += o4[ct][i] * sc;
            }
    }
    __syncthreads();

    // ---- final store: thread t -> row t>>3 (0..63), cols (t&7)*16..+16
    {
        int row = t >> 3, d0 = (t & 7) * 16;
        float inv = 1.0f / gl_lds[row >> 5][row & 31];
        float* dst = out + (size_t)(qrow0 + row) * DK_ + d0;
#pragma unroll
        for (int j = 0; j < 16; j += 4) {
            float4 v;
            v.x = u.e.ob[row][d0 + j]     * inv;
            v.y = u.e.ob[row][d0 + j + 1] * inv;
            v.z = u.e.ob[row][d0 + j + 2] * inv;
            v.w = u.e.ob[row][d0 + j + 3] * inv;
            *(float4*)(dst + j) = v;
        }
    }
}

// ---------------------------------------------------------------------------
extern "C" void kernel_launch(void* const* d_in, const int* in_sizes, int n_in,
                              void* d_out, int out_size, void* d_ws, size_t ws_size,
                              hipStream_t stream) {
    const float* q  = (const float*)d_in[0];
    const float* k  = (const float*)d_in[1];
    const float* v  = (const float*)d_in[2];
    const float* wq = (const float*)d_in[3];
    const float* wk = (const float*)d_in[4];
    const float* wv = (const float*)d_in[5];
    float* out = (float*)d_out;

    char* ws = (char*)d_ws;
    u16* WT  = (u16*)ws;                                   // 786432 B
    u16* qp  = (u16*)(ws + 786432);                        // 4 MB
    u16* kp  = (u16*)(ws + 786432 + 4194304);              // 4 MB
    u16* vpT = (u16*)(ws + 786432 + 2 * 4194304);          // 4 MB

    prep_wt<<<dim3(1536), dim3(256), 0, stream>>>(wq, wk, wv, WT);
    proj<<<dim3(256, 3), dim3(256), 0, stream>>>(q, k, v, WT, qp, kp, vpT);
    attn<<<dim3(256), dim3(512), 0, stream>>>(qp, kp, vpT, out);
}